// Round 5
// baseline (383.582 us; speedup 1.0000x reference)
//
#include <hip/hip_runtime.h>
#include <hip/hip_bf16.h>

#define N_NODES 10000
#define N_EDGES 320000
#define CDIM    256

typedef __attribute__((ext_vector_type(8))) short short8;
typedef __attribute__((ext_vector_type(8))) _Float16 half8;
typedef __attribute__((ext_vector_type(4))) _Float16 half4;
typedef __attribute__((ext_vector_type(4))) float floatx4;

__device__ __forceinline__ float b2f(unsigned short u) {
  return __uint_as_float(((unsigned int)u) << 16);
}

// ---- ws offsets (bytes), total ~11.99 MB ----
#define OFF_FLAG   0
#define OFF_CNT    4096
#define OFF_CUR    45056
#define OFF_S2     86016
#define OFF_RS     166912
#define OFF_INVC   207872
#define OFF_EWF    248832
#define OFF_BIASF  254976
#define OFF_ALPHAF 258048
#define OFF_COLV   319488
#define OFF_WCAT   959488
#define OFF_HN     1745920
#define OFF_HX     6865920
// OFF_HX end: 11985920

// ---------------- input dtype sniffer ----------------
// Low 16 bits of each word as bf16: bf16 data -> element 2i ~ N(0,1), in range
// ~99.9%; fp32 data -> uniform mantissa bits, in range ~6%.
__global__ void k_sniff(const unsigned int* __restrict__ xraw, int* __restrict__ flag) {
  if (threadIdx.x == 0 && blockIdx.x == 0) {
    int c = 0;
    for (int i = 0; i < 256; ++i) {
      float v = b2f((unsigned short)(xraw[i] & 0xFFFFu));
      float av = fabsf(v);
      if (av > 9.765625e-4f && av < 32.f) c++;
    }
    *flag = (c >= 128) ? 1 : 0;   // 1 = bf16 inputs, 0 = fp32 inputs
  }
}

__device__ __forceinline__ float loadIn(const void* src, int i, int isbf16) {
  return isbf16 ? b2f(((const unsigned short*)src)[i]) : ((const float*)src)[i];
}

// convert -> f32
__global__ __launch_bounds__(256) void k_convf(const void* __restrict__ src, float* __restrict__ dst,
                                               int n, const int* __restrict__ flag) {
  int i = blockIdx.x * 256 + threadIdx.x;
  if (i >= n) return;
  dst[i] = loadIn(src, i, *flag);
}

// convert -> f16
__global__ __launch_bounds__(256) void k_convg(const void* __restrict__ src, _Float16* __restrict__ dst,
                                               int n, const int* __restrict__ flag) {
  int i = blockIdx.x * 256 + threadIdx.x;
  if (i >= n) return;
  dst[i] = (_Float16)loadIn(src, i, *flag);
}

// ---------------- preprocessing ----------------
__global__ __launch_bounds__(256) void k_hist(const int* __restrict__ ei, const void* __restrict__ ea,
                                              int* __restrict__ cnt, float* __restrict__ s2,
                                              const int* __restrict__ flag) {
  int e = blockIdx.x * 256 + threadIdx.x;
  if (e >= N_EDGES) return;
  int d = ei[N_EDGES + e];
  if ((unsigned)d >= N_NODES) return;
  atomicAdd(&cnt[d], 1);
  float a0 = loadIn(ea, 2 * e, *flag);
  float a1 = loadIn(ea, 2 * e + 1, *flag);
  atomicAdd(&s2[2 * d],     a0);
  atomicAdd(&s2[2 * d + 1], a1);
}

__global__ __launch_bounds__(1024) void k_scan(const int* __restrict__ cnt,
                                               int* __restrict__ rs, float* __restrict__ invc) {
  __shared__ int lds[1024];
  const int t = threadIdx.x;
  const int base = t * 10;
  int loc[10];
  int sum = 0;
#pragma unroll
  for (int i = 0; i < 10; ++i) {
    int idx = base + i;
    int v = (idx < N_NODES) ? cnt[idx] : 0;
    loc[i] = v; sum += v;
  }
  lds[t] = sum; __syncthreads();
  for (int off = 1; off < 1024; off <<= 1) {
    int v = 0;
    if (t >= off) v = lds[t - off];
    __syncthreads();
    if (t >= off) lds[t] += v;
    __syncthreads();
  }
  int ex = lds[t] - sum;
#pragma unroll
  for (int i = 0; i < 10; ++i) {
    int idx = base + i;
    if (idx < N_NODES) {
      rs[idx] = ex; ex += loc[i];
      invc[idx] = (loc[i] > 0) ? (1.0f / (float)loc[i]) : 0.0f;
    }
  }
  if (t == 1023) rs[N_NODES] = lds[1023];
}

__global__ __launch_bounds__(256) void k_scatter(const int* __restrict__ ei, const int* __restrict__ rs,
                                                 int* __restrict__ cursor, unsigned short* __restrict__ colv) {
  int e = blockIdx.x * 256 + threadIdx.x;
  if (e >= N_EDGES) return;
  int d = ei[N_EDGES + e];
  if ((unsigned)d >= N_NODES) return;
  int pos = rs[d] + atomicAdd(&cursor[d], 1);
  if ((unsigned)pos < N_EDGES) colv[pos] = (unsigned short)ei[e];
}

// WcatT[l][n][k] = (n<256 ? neigh_w[l][k][n] : node_w[l][k][n-256]), f16
__global__ __launch_bounds__(256) void k_pack(const void* __restrict__ neigh_w, const void* __restrict__ node_w,
                                              _Float16* __restrict__ wcatT, const int* __restrict__ flag) {
  int idx = blockIdx.x * 256 + threadIdx.x;   // exactly 3*512*256
  int l = idx >> 17;
  int rem = idx & 131071;
  int n = rem >> 8;
  int k = rem & 255;
  int off = (n < 256) ? (l * 65536 + k * 256 + n) : (l * 65536 + k * 256 + (n - 256));
  const void* src = (n < 256) ? neigh_w : node_w;
  wcatT[idx] = (_Float16)loadIn(src, off, *flag);
}

// ---------------- GEMM: [N x 256] @ [256 x 512] via B^T, fp16 MFMA ----------------
// block tile 128x128, 4 waves (2x2), wave tile 64x64, BK=32, mfma 16x16x32 f16
__global__ __launch_bounds__(256) void k_gemm(const _Float16* __restrict__ A,   // [N][256] f16
                                              const _Float16* __restrict__ BT,  // [512][256] f16
                                              _Float16* __restrict__ hn,        // [N][256] f16
                                              _Float16* __restrict__ hx) {      // [N][256] f16
  __shared__ _Float16 As[128 * 32];
  __shared__ _Float16 Bs[128 * 32];
  const int tid = threadIdx.x;
  const int wv = tid >> 6;
  const int lane = tid & 63;
  const int m0 = blockIdx.x * 128;
  const int n0 = blockIdx.y * 128;
  const int wy = wv >> 1, wx = wv & 1;

  floatx4 acc[4][4];
#pragma unroll
  for (int i = 0; i < 4; ++i)
#pragma unroll
    for (int j = 0; j < 4; ++j) acc[i][j] = (floatx4){0.f, 0.f, 0.f, 0.f};

  // staging: thread t -> tile row t>>1, k-half (t&1)*16; clamp M rows
  const int sr = tid >> 1;
  const int sk = (tid & 1) * 16;
  int arow = m0 + sr; if (arow >= N_NODES) arow = N_NODES - 1;
  const _Float16* Ag = A  + (size_t)arow * 256 + sk;
  const _Float16* Bg = BT + (size_t)(n0 + sr) * 256 + sk;
  _Float16* Asp = &As[sr * 32 + sk];
  _Float16* Bsp = &Bs[sr * 32 + sk];

  const int mrow = 64 * wy + (lane & 15);
  const int nrow = 64 * wx + (lane & 15);
  const int q8 = (lane >> 4) * 8;

  for (int kt = 0; kt < 8; ++kt) {
    const int k0 = kt * 32;
    half8 av0 = *(const half8*)(Ag + k0);
    half8 av1 = *(const half8*)(Ag + k0 + 8);
    half8 bv0 = *(const half8*)(Bg + k0);
    half8 bv1 = *(const half8*)(Bg + k0 + 8);
    __syncthreads();
    *(half8*)Asp       = av0;
    *(half8*)(Asp + 8) = av1;
    *(half8*)Bsp       = bv0;
    *(half8*)(Bsp + 8) = bv1;
    __syncthreads();
    half8 af[4], bf[4];
#pragma unroll
    for (int i = 0; i < 4; ++i) af[i] = *(const half8*)&As[(mrow + 16 * i) * 32 + q8];
#pragma unroll
    for (int j = 0; j < 4; ++j) bf[j] = *(const half8*)&Bs[(nrow + 16 * j) * 32 + q8];
#pragma unroll
    for (int i = 0; i < 4; ++i)
#pragma unroll
      for (int j = 0; j < 4; ++j)
        acc[i][j] = __builtin_amdgcn_mfma_f32_16x16x32_f16(af[i], bf[j], acc[i][j], 0, 0, 0);
  }

  // C/D layout: col = lane&15, row = 4*(lane>>4) + r  [m89-verified, dtype-independent]
  const int colb = n0 + 64 * wx + (lane & 15);
  const int rowb = m0 + 64 * wy + 4 * (lane >> 4);
#pragma unroll
  for (int i = 0; i < 4; ++i) {
#pragma unroll
    for (int j = 0; j < 4; ++j) {
      const int cn = colb + 16 * j;
#pragma unroll
      for (int r = 0; r < 4; ++r) {
        const int rw = rowb + 16 * i + r;
        if (rw < N_NODES) {
          float v = acc[i][j][r];
          if (cn < 256) hn[rw * 256 + cn] = (_Float16)v;
          else          hx[rw * 256 + (cn - 256)] = (_Float16)v;
        }
      }
    }
  }
}

// ---------------- aggregate + update + KAF ----------------
// final==0: write f16 h to hmid ; final==1: write f32 to fout
__global__ __launch_bounds__(256) void k_update(const int* __restrict__ rs, const unsigned short* __restrict__ colv,
                                                const float* __restrict__ invc, const float* __restrict__ s2,
                                                const _Float16* __restrict__ hn, const _Float16* __restrict__ hx,
                                                const float* __restrict__ ew,     // [2][256] f32
                                                const float* __restrict__ bias,   // [256]    f32
                                                const float* __restrict__ alpha,  // [256][20] f32
                                                _Float16* __restrict__ hmid, float* __restrict__ fout,
                                                int final_layer) {
  const int wv = threadIdx.x >> 6;
  const int lane = threadIdx.x & 63;
  const int n = blockIdx.x * 4 + wv;           // 2500*4 == N_NODES
  int beg = rs[n], end = rs[n + 1];
  beg = max(0, min(beg, N_EDGES));
  end = max(beg, min(end, N_EDGES));
  const half4* hn4 = (const half4*)hn;
  float a0 = 0.f, a1 = 0.f, a2 = 0.f, a3 = 0.f;
  for (int e = beg; e < end; ++e) {
    int sA = colv[e];
    if (sA >= N_NODES) sA = 0;
    half4 v0 = hn4[sA * 64 + lane];
    a0 += (float)v0.x; a1 += (float)v0.y; a2 += (float)v0.z; a3 += (float)v0.w;
  }
  const float ic = invc[n];
  const float t0 = s2[2 * n], t1 = s2[2 * n + 1];
  const half4  hv = ((const half4*)hx)[n * 64 + lane];
  const float4 e0 = ((const float4*)ew)[lane];
  const float4 e1 = ((const float4*)ew)[64 + lane];
  const float4 bi = ((const float4*)bias)[lane];
  float s[4];
  s[0] = (a0 + t0 * e0.x + t1 * e1.x) * ic + (float)hv.x + bi.x;
  s[1] = (a1 + t0 * e0.y + t1 * e1.y) * ic + (float)hv.y + bi.y;
  s[2] = (a2 + t0 * e0.z + t1 * e1.z) * ic + (float)hv.z + bi.z;
  s[3] = (a3 + t0 * e0.w + t1 * e1.w) * ic + (float)hv.w + bi.w;

  const int c0 = lane * 4;
  const float G = -0.705078125f;               // -0.5/(2*interval)^2, interval = 8/19
  float o[4];
#pragma unroll
  for (int k = 0; k < 4; ++k) {
    const float4* ar = (const float4*)(alpha + (c0 + k) * 20);
    const float sv = s[k];
    float ov = 0.f;
#pragma unroll
    for (int g = 0; g < 5; ++g) {
      const float4 a4 = ar[g];
      const float dp = 8.0f / 19.0f;
      const float pb = -4.0f + dp * (float)(4 * g);
      float x0 = sv - pb;
      float x1 = sv - (pb + dp);
      float x2 = sv - (pb + 2.f * dp);
      float x3 = sv - (pb + 3.f * dp);
      ov += a4.x * __expf(G * x0 * x0);
      ov += a4.y * __expf(G * x1 * x1);
      ov += a4.z * __expf(G * x2 * x2);
      ov += a4.w * __expf(G * x3 * x3);
    }
    o[k] = ov;
  }
  if (final_layer) {
    float4 w; w.x = o[0]; w.y = o[1]; w.z = o[2]; w.w = o[3];
    ((float4*)fout)[n * 64 + lane] = w;
  } else {
    half4 w; w.x = (_Float16)o[0]; w.y = (_Float16)o[1]; w.z = (_Float16)o[2]; w.w = (_Float16)o[3];
    ((half4*)hmid)[n * 64 + lane] = w;
  }
}

// ---------------- launch ----------------
extern "C" void kernel_launch(void* const* d_in, const int* in_sizes, int n_in,
                              void* d_out, int out_size, void* d_ws, size_t ws_size,
                              hipStream_t stream) {
  const void* x       = d_in[0];
  const int*  ei      = (const int*)d_in[1];
  const void* ea      = d_in[2];
  const void* node_w  = d_in[3];
  const void* edge_w  = d_in[4];
  const void* neigh_w = d_in[5];
  const void* bias    = d_in[6];
  const void* alpha   = d_in[7];

  char* w = (char*)d_ws;
  int*            flag   = (int*)(w + OFF_FLAG);
  int*            cnt    = (int*)(w + OFF_CNT);
  int*            cursor = (int*)(w + OFF_CUR);
  float*          s2     = (float*)(w + OFF_S2);
  int*            rs     = (int*)(w + OFF_RS);
  float*          invc   = (float*)(w + OFF_INVC);
  float*          ewf    = (float*)(w + OFF_EWF);
  float*          biasf  = (float*)(w + OFF_BIASF);
  float*          alphaf = (float*)(w + OFF_ALPHAF);
  unsigned short* colv   = (unsigned short*)(w + OFF_COLV);
  _Float16*       wcatT  = (_Float16*)(w + OFF_WCAT);
  _Float16*       hn     = (_Float16*)(w + OFF_HN);
  _Float16*       hx     = (_Float16*)(w + OFF_HX);
  float*          fout   = (float*)d_out;          // final output: fp32
  _Float16*       hB     = (_Float16*)d_out;       // low half doubles as f16 h ping
                                                   // (fully consumed by each k_gemm
                                                   //  before any k_update rewrites it)

  hipMemsetAsync(w, 0, OFF_RS, stream);  // flag, cnt, cursor, s2
  k_sniff<<<1, 64, 0, stream>>>((const unsigned int*)x, flag);
  k_convg<<<(N_NODES * CDIM + 255) / 256, 256, 0, stream>>>(x, hB, N_NODES * CDIM, flag);
  k_convf<<<6,  256, 0, stream>>>(edge_w, ewf,    3 * 2 * 256,  flag);
  k_convf<<<3,  256, 0, stream>>>(bias,   biasf,  3 * 256,      flag);
  k_convf<<<60, 256, 0, stream>>>(alpha,  alphaf, 3 * 256 * 20, flag);
  k_hist<<<(N_EDGES + 255) / 256, 256, 0, stream>>>(ei, ea, cnt, s2, flag);
  k_scan<<<1, 1024, 0, stream>>>(cnt, rs, invc);
  k_scatter<<<(N_EDGES + 255) / 256, 256, 0, stream>>>(ei, rs, cursor, colv);
  k_pack<<<1536, 256, 0, stream>>>(neigh_w, node_w, wcatT, flag);

  for (int l = 0; l < 3; ++l) {
    k_gemm<<<dim3(79, 4, 1), 256, 0, stream>>>(hB, wcatT + l * 131072, hn, hx);
    k_update<<<2500, 256, 0, stream>>>(rs, colv, invc, s2, hn, hx,
                                       ewf + l * 512, biasf + l * 256, alphaf + l * 5120,
                                       hB, fout, (l == 2) ? 1 : 0);
  }
}

// Round 6
// 337.780 us; speedup vs baseline: 1.1356x; 1.1356x over previous
//
#include <hip/hip_runtime.h>
#include <hip/hip_bf16.h>

#define N_NODES 10000
#define N_EDGES 320000
#define CDIM    256

typedef __attribute__((ext_vector_type(8))) short short8;
typedef __attribute__((ext_vector_type(8))) _Float16 half8;
typedef __attribute__((ext_vector_type(4))) _Float16 half4;
typedef __attribute__((ext_vector_type(4))) float floatx4;

__device__ __forceinline__ float b2f(unsigned short u) {
  return __uint_as_float(((unsigned int)u) << 16);
}

// ---- ws offsets (bytes), total ~11.99 MB ----
#define OFF_FLAG   0
#define OFF_CNT    4096
#define OFF_CUR    45056
#define OFF_S2     86016
#define OFF_RS     166912
#define OFF_INVC   207872
#define OFF_EWF    248832
#define OFF_BIASF  254976
#define OFF_ALPHAF 258048
#define OFF_COLV   319488
#define OFF_WCAT   959488
#define OFF_HN     1745920
#define OFF_HX     6865920

// ---------------- input dtype sniffer ----------------
__global__ void k_sniff(const unsigned int* __restrict__ xraw, int* __restrict__ flag) {
  if (threadIdx.x == 0 && blockIdx.x == 0) {
    int c = 0;
    for (int i = 0; i < 256; ++i) {
      float v = b2f((unsigned short)(xraw[i] & 0xFFFFu));
      float av = fabsf(v);
      if (av > 9.765625e-4f && av < 32.f) c++;
    }
    *flag = (c >= 128) ? 1 : 0;   // 1 = bf16 inputs, 0 = fp32 inputs
  }
}

__device__ __forceinline__ float loadIn(const void* src, int i, int isbf16) {
  return isbf16 ? b2f(((const unsigned short*)src)[i]) : ((const float*)src)[i];
}

// x -> f16
__global__ __launch_bounds__(256) void k_convg(const void* __restrict__ src, _Float16* __restrict__ dst,
                                               int n, const int* __restrict__ flag) {
  int i = blockIdx.x * 256 + threadIdx.x;
  if (i >= n) return;
  dst[i] = (_Float16)loadIn(src, i, *flag);
}

// fused small-param convert -> f32 (ew:1536, bias:768, alpha:15360 => 17664 = 69*256)
__global__ __launch_bounds__(256) void k_convp(const void* __restrict__ ew, const void* __restrict__ bias,
                                               const void* __restrict__ alpha,
                                               float* __restrict__ ewf, float* __restrict__ biasf,
                                               float* __restrict__ alphaf, const int* __restrict__ flag) {
  int i = blockIdx.x * 256 + threadIdx.x;
  int f = *flag;
  if (i < 1536)      ewf[i]           = loadIn(ew,    i,        f);
  else if (i < 2304) biasf[i - 1536]  = loadIn(bias,  i - 1536, f);
  else               alphaf[i - 2304] = loadIn(alpha, i - 2304, f);
}

// ---------------- preprocessing ----------------
__global__ __launch_bounds__(256) void k_hist(const int* __restrict__ ei, const void* __restrict__ ea,
                                              int* __restrict__ cnt, float* __restrict__ s2,
                                              const int* __restrict__ flag) {
  int e = blockIdx.x * 256 + threadIdx.x;
  if (e >= N_EDGES) return;
  int d = ei[N_EDGES + e];
  if ((unsigned)d >= N_NODES) return;
  atomicAdd(&cnt[d], 1);
  float a0 = loadIn(ea, 2 * e,     *flag);
  float a1 = loadIn(ea, 2 * e + 1, *flag);
  atomicAdd(&s2[2 * d],     a0);
  atomicAdd(&s2[2 * d + 1], a1);
}

__global__ __launch_bounds__(1024) void k_scan(const int* __restrict__ cnt,
                                               int* __restrict__ rs, float* __restrict__ invc) {
  __shared__ int lds[1024];
  const int t = threadIdx.x;
  const int base = t * 10;
  int loc[10];
  int sum = 0;
#pragma unroll
  for (int i = 0; i < 10; ++i) {
    int idx = base + i;
    int v = (idx < N_NODES) ? cnt[idx] : 0;
    loc[i] = v; sum += v;
  }
  lds[t] = sum; __syncthreads();
  for (int off = 1; off < 1024; off <<= 1) {
    int v = 0;
    if (t >= off) v = lds[t - off];
    __syncthreads();
    if (t >= off) lds[t] += v;
    __syncthreads();
  }
  int ex = lds[t] - sum;
#pragma unroll
  for (int i = 0; i < 10; ++i) {
    int idx = base + i;
    if (idx < N_NODES) {
      rs[idx] = ex; ex += loc[i];
      invc[idx] = (loc[i] > 0) ? (1.0f / (float)loc[i]) : 0.0f;
    }
  }
  if (t == 1023) rs[N_NODES] = lds[1023];
}

__global__ __launch_bounds__(256) void k_scatter(const int* __restrict__ ei, const int* __restrict__ rs,
                                                 int* __restrict__ cursor, unsigned short* __restrict__ colv) {
  int e = blockIdx.x * 256 + threadIdx.x;
  if (e >= N_EDGES) return;
  int d = ei[N_EDGES + e];
  if ((unsigned)d >= N_NODES) return;
  int pos = rs[d] + atomicAdd(&cursor[d], 1);
  if ((unsigned)pos < N_EDGES) colv[pos] = (unsigned short)ei[e];
}

// WcatT[l][n][k] via LDS 32x32 tile transpose; grid (8 k-tiles, 16 n-tiles, 3)
__global__ __launch_bounds__(256) void k_pack(const void* __restrict__ neigh_w, const void* __restrict__ node_w,
                                              _Float16* __restrict__ wcatT, const int* __restrict__ flag) {
  __shared__ float t[32][33];
  const int f = *flag;
  const int k0 = blockIdx.x * 32;
  const int n0 = blockIdx.y * 32;
  const int l  = blockIdx.z;
  const int tx = threadIdx.x & 31;
  const int ty = threadIdx.x >> 5;   // 0..7
  const void* src = (n0 < 256) ? neigh_w : node_w;
  const int nb = (n0 < 256) ? n0 : (n0 - 256);
#pragma unroll
  for (int p = 0; p < 4; ++p) {
    int k = k0 + ty + p * 8;
    t[ty + p * 8][tx] = loadIn(src, l * 65536 + k * 256 + (nb + tx), f);   // coalesced in n
  }
  __syncthreads();
#pragma unroll
  for (int p = 0; p < 4; ++p) {
    int n = n0 + ty + p * 8;
    wcatT[(size_t)l * 131072 + n * 256 + (k0 + tx)] = (_Float16)t[tx][ty + p * 8];  // coalesced in k
  }
}

// ---------------- GEMM: [N x 256] @ [256 x 512] via B^T, fp16 MFMA ----------------
__global__ __launch_bounds__(256) void k_gemm(const _Float16* __restrict__ A,   // [N][256] f16
                                              const _Float16* __restrict__ BT,  // [512][256] f16
                                              _Float16* __restrict__ hn,        // [N][256] f16
                                              _Float16* __restrict__ hx) {      // [N][256] f16
  __shared__ _Float16 As[128 * 32];
  __shared__ _Float16 Bs[128 * 32];
  const int tid = threadIdx.x;
  const int wv = tid >> 6;
  const int lane = tid & 63;
  const int m0 = blockIdx.x * 128;
  const int n0 = blockIdx.y * 128;
  const int wy = wv >> 1, wx = wv & 1;

  floatx4 acc[4][4];
#pragma unroll
  for (int i = 0; i < 4; ++i)
#pragma unroll
    for (int j = 0; j < 4; ++j) acc[i][j] = (floatx4){0.f, 0.f, 0.f, 0.f};

  const int sr = tid >> 1;
  const int sk = (tid & 1) * 16;
  int arow = m0 + sr; if (arow >= N_NODES) arow = N_NODES - 1;
  const _Float16* Ag = A  + (size_t)arow * 256 + sk;
  const _Float16* Bg = BT + (size_t)(n0 + sr) * 256 + sk;
  _Float16* Asp = &As[sr * 32 + sk];
  _Float16* Bsp = &Bs[sr * 32 + sk];

  const int mrow = 64 * wy + (lane & 15);
  const int nrow = 64 * wx + (lane & 15);
  const int q8 = (lane >> 4) * 8;

  for (int kt = 0; kt < 8; ++kt) {
    const int k0 = kt * 32;
    half8 av0 = *(const half8*)(Ag + k0);
    half8 av1 = *(const half8*)(Ag + k0 + 8);
    half8 bv0 = *(const half8*)(Bg + k0);
    half8 bv1 = *(const half8*)(Bg + k0 + 8);
    __syncthreads();
    *(half8*)Asp       = av0;
    *(half8*)(Asp + 8) = av1;
    *(half8*)Bsp       = bv0;
    *(half8*)(Bsp + 8) = bv1;
    __syncthreads();
    half8 af[4], bf[4];
#pragma unroll
    for (int i = 0; i < 4; ++i) af[i] = *(const half8*)&As[(mrow + 16 * i) * 32 + q8];
#pragma unroll
    for (int j = 0; j < 4; ++j) bf[j] = *(const half8*)&Bs[(nrow + 16 * j) * 32 + q8];
#pragma unroll
    for (int i = 0; i < 4; ++i)
#pragma unroll
      for (int j = 0; j < 4; ++j)
        acc[i][j] = __builtin_amdgcn_mfma_f32_16x16x32_f16(af[i], bf[j], acc[i][j], 0, 0, 0);
  }

  const int colb = n0 + 64 * wx + (lane & 15);
  const int rowb = m0 + 64 * wy + 4 * (lane >> 4);
#pragma unroll
  for (int i = 0; i < 4; ++i) {
#pragma unroll
    for (int j = 0; j < 4; ++j) {
      const int cn = colb + 16 * j;
#pragma unroll
      for (int r = 0; r < 4; ++r) {
        const int rw = rowb + 16 * i + r;
        if (rw < N_NODES) {
          float v = acc[i][j][r];
          if (cn < 256) hn[rw * 256 + cn] = (_Float16)v;
          else          hx[rw * 256 + (cn - 256)] = (_Float16)v;
        }
      }
    }
  }
}

// ---------------- aggregate + update + KAF ----------------
// one wave per node; two 32-lane halves process 2 edges/iter, 16B (half8) gathers,
// cooperative index load + shfl distribution, fp16 packed accumulation.
__global__ __launch_bounds__(256) void k_update(const int* __restrict__ rs, const unsigned short* __restrict__ colv,
                                                const float* __restrict__ invc, const float* __restrict__ s2,
                                                const _Float16* __restrict__ hn, const _Float16* __restrict__ hx,
                                                const float* __restrict__ ew,     // [2][256] f32
                                                const float* __restrict__ bias,   // [256]    f32
                                                const float* __restrict__ alpha,  // [256][20] f32
                                                _Float16* __restrict__ hmid, float* __restrict__ fout,
                                                int final_layer) {
  const int wv   = threadIdx.x >> 6;
  const int lane = threadIdx.x & 63;
  const int hf   = lane >> 5;          // which half-wave
  const int l5   = lane & 31;
  const int n = blockIdx.x * 4 + wv;   // 2500*4 == N_NODES
  int beg = rs[n], end = rs[n + 1];
  beg = max(0, min(beg, N_EDGES));
  end = max(beg, min(end, N_EDGES));

  half8 acc0 = (half8)(_Float16)0.f, acc1 = (half8)(_Float16)0.f;
  for (int base = beg; base < end; base += 64) {
    const int cnt = min(64, end - base);
    int myIdx = 0;
    if (base + lane < end) myIdx = (int)colv[base + lane];   // coalesced index load
    int j = 0;
    for (; j + 4 <= cnt; j += 4) {                           // 4 edges in flight
      int sA = __shfl(myIdx, j + hf);
      int sB = __shfl(myIdx, j + 2 + hf);
      if ((unsigned)sA >= N_NODES) sA = 0;
      if ((unsigned)sB >= N_NODES) sB = 0;
      half8 vA = *(const half8*)(hn + (size_t)sA * 256 + l5 * 8);
      half8 vB = *(const half8*)(hn + (size_t)sB * 256 + l5 * 8);
      acc0 += vA;
      acc1 += vB;
    }
    for (; j + 2 <= cnt; j += 2) {
      int sA = __shfl(myIdx, j + hf);
      if ((unsigned)sA >= N_NODES) sA = 0;
      acc0 += *(const half8*)(hn + (size_t)sA * 256 + l5 * 8);
    }
    if (j < cnt) {
      int sA = __shfl(myIdx, j);
      if (hf == 0) {
        if ((unsigned)sA >= N_NODES) sA = 0;
        acc0 += *(const half8*)(hn + (size_t)sA * 256 + l5 * 8);
      }
    }
  }
  acc0 += acc1;
  // combine the two half-waves (same channels, different edges)
  union { half8 h; unsigned int u[4]; } me, ot;
  me.h = acc0;
#pragma unroll
  for (int r = 0; r < 4; ++r) ot.u[r] = (unsigned int)__shfl_xor((int)me.u[r], 32);
  acc0 = me.h + ot.h;

  // channel remap: this lane handles channels c0..c0+3
  const int c0 = l5 * 8 + hf * 4;
  float a0, a1, a2, a3;
  if (hf) { a0 = (float)acc0[4]; a1 = (float)acc0[5]; a2 = (float)acc0[6]; a3 = (float)acc0[7]; }
  else    { a0 = (float)acc0[0]; a1 = (float)acc0[1]; a2 = (float)acc0[2]; a3 = (float)acc0[3]; }

  const int q = c0 >> 2;
  const float ic = invc[n];
  const float t0 = s2[2 * n], t1 = s2[2 * n + 1];
  const half4  hv = ((const half4*)hx)[n * 64 + q];
  const float4 e0 = ((const float4*)ew)[q];
  const float4 e1 = ((const float4*)ew)[64 + q];
  const float4 bi = ((const float4*)bias)[q];
  float s[4];
  s[0] = (a0 + t0 * e0.x + t1 * e1.x) * ic + (float)hv.x + bi.x;
  s[1] = (a1 + t0 * e0.y + t1 * e1.y) * ic + (float)hv.y + bi.y;
  s[2] = (a2 + t0 * e0.z + t1 * e1.z) * ic + (float)hv.z + bi.z;
  s[3] = (a3 + t0 * e0.w + t1 * e1.w) * ic + (float)hv.w + bi.w;

  const float G = -0.705078125f;               // -0.5/(2*interval)^2, interval = 8/19
  float o[4];
#pragma unroll
  for (int k = 0; k < 4; ++k) {
    const float4* ar = (const float4*)(alpha + (c0 + k) * 20);
    const float sv = s[k];
    float ov = 0.f;
#pragma unroll
    for (int g = 0; g < 5; ++g) {
      const float4 a4 = ar[g];
      const float dp = 8.0f / 19.0f;
      const float pb = -4.0f + dp * (float)(4 * g);
      float x0 = sv - pb;
      float x1 = sv - (pb + dp);
      float x2 = sv - (pb + 2.f * dp);
      float x3 = sv - (pb + 3.f * dp);
      ov += a4.x * __expf(G * x0 * x0);
      ov += a4.y * __expf(G * x1 * x1);
      ov += a4.z * __expf(G * x2 * x2);
      ov += a4.w * __expf(G * x3 * x3);
    }
    o[k] = ov;
  }
  if (final_layer) {
    float4 w; w.x = o[0]; w.y = o[1]; w.z = o[2]; w.w = o[3];
    ((float4*)fout)[n * 64 + q] = w;
  } else {
    half4 w; w.x = (_Float16)o[0]; w.y = (_Float16)o[1]; w.z = (_Float16)o[2]; w.w = (_Float16)o[3];
    ((half4*)hmid)[n * 64 + q] = w;
  }
}

// ---------------- launch ----------------
extern "C" void kernel_launch(void* const* d_in, const int* in_sizes, int n_in,
                              void* d_out, int out_size, void* d_ws, size_t ws_size,
                              hipStream_t stream) {
  const void* x       = d_in[0];
  const int*  ei      = (const int*)d_in[1];
  const void* ea      = d_in[2];
  const void* node_w  = d_in[3];
  const void* edge_w  = d_in[4];
  const void* neigh_w = d_in[5];
  const void* bias    = d_in[6];
  const void* alpha   = d_in[7];

  char* w = (char*)d_ws;
  int*            flag   = (int*)(w + OFF_FLAG);
  int*            cnt    = (int*)(w + OFF_CNT);
  int*            cursor = (int*)(w + OFF_CUR);
  float*          s2     = (float*)(w + OFF_S2);
  int*            rs     = (int*)(w + OFF_RS);
  float*          invc   = (float*)(w + OFF_INVC);
  float*          ewf    = (float*)(w + OFF_EWF);
  float*          biasf  = (float*)(w + OFF_BIASF);
  float*          alphaf = (float*)(w + OFF_ALPHAF);
  unsigned short* colv   = (unsigned short*)(w + OFF_COLV);
  _Float16*       wcatT  = (_Float16*)(w + OFF_WCAT);
  _Float16*       hn     = (_Float16*)(w + OFF_HN);
  _Float16*       hx     = (_Float16*)(w + OFF_HX);
  float*          fout   = (float*)d_out;
  _Float16*       hB     = (_Float16*)d_out;   // f16 h ping (consumed by k_gemm before rewrite)

  hipMemsetAsync(w, 0, OFF_RS, stream);  // flag, cnt, cursor, s2
  k_sniff<<<1, 64, 0, stream>>>((const unsigned int*)x, flag);
  k_convg<<<(N_NODES * CDIM + 255) / 256, 256, 0, stream>>>(x, hB, N_NODES * CDIM, flag);
  k_convp<<<69, 256, 0, stream>>>(edge_w, bias, alpha, ewf, biasf, alphaf, flag);
  k_hist<<<(N_EDGES + 255) / 256, 256, 0, stream>>>(ei, ea, cnt, s2, flag);
  k_scan<<<1, 1024, 0, stream>>>(cnt, rs, invc);
  k_scatter<<<(N_EDGES + 255) / 256, 256, 0, stream>>>(ei, rs, cursor, colv);
  k_pack<<<dim3(8, 16, 3), 256, 0, stream>>>(neigh_w, node_w, wcatT, flag);

  for (int l = 0; l < 3; ++l) {
    k_gemm<<<dim3(79, 4, 1), 256, 0, stream>>>(hB, wcatT + l * 131072, hn, hx);
    k_update<<<2500, 256, 0, stream>>>(rs, colv, invc, s2, hn, hx,
                                       ewf + l * 512, biasf + l * 256, alphaf + l * 5120,
                                       hB, fout, (l == 2) ? 1 : 0);
  }
}